// Round 10
// baseline (224.016 us; speedup 1.0000x reference)
//
#include <hip/hip_runtime.h>
#include <hip/hip_bf16.h>
#include <stdint.h>
#include <math.h>

// Problem constants
#define T_DIM 2048
#define B_DIM 2
#define E_DIM 1024
#define H_DIM 16
#define DH    64
#define MROWS (T_DIM * B_DIM)   // 4096
#define QKVN  (3 * E_DIM)       // 3072

typedef __attribute__((ext_vector_type(8))) __bf16 bf16x8;
typedef __attribute__((ext_vector_type(4))) float f32x4;
typedef __attribute__((ext_vector_type(4))) uint32_t u32x4;
typedef __attribute__((ext_vector_type(2))) uint32_t u32x2;

typedef __attribute__((address_space(1))) const uint32_t gu32;
typedef __attribute__((address_space(3))) uint32_t lu32;

// async global->LDS, 16B per lane; LDS dest = wave-uniform base + lane*16
#define GLL(gp, lp) __builtin_amdgcn_global_load_lds((gu32*)(gp), (lu32*)(lp), 16, 0, 0)

// Q prescale: 0.125 (=DH^-0.5) * log2(e), so attn uses exp2 (bare v_exp_f32)
#define QSCALE 0.18033688011112042f

// raw 2^x (v_exp_f32). Guarded: builtin if present, else OCML exp2f.
#if __has_builtin(__builtin_amdgcn_exp2f)
#define EXP2(x) __builtin_amdgcn_exp2f(x)
#else
#define EXP2(x) exp2f(x)
#endif

static __device__ __forceinline__ unsigned short f2bf(float f) {
    uint32_t u = __float_as_uint(f);
    u += 0x7FFFu + ((u >> 16) & 1u);   // RNE
    return (unsigned short)(u >> 16);
}

// ---------------------------------------------------------------- fused fp32 -> bf16 (3 tensors)
__global__ void k_cvt3(const float* __restrict__ q,  const float* __restrict__ w,
                       const float* __restrict__ o,
                       unsigned short* __restrict__ qo, unsigned short* __restrict__ wo,
                       unsigned short* __restrict__ oo) {
    long i = (long)(blockIdx.x * 256 + threadIdx.x) * 8;
    const float* src; unsigned short* dst; long off;
    if (i < 4194304)      { src = q; dst = qo; off = i; }             // query 4096x1024
    else if (i < 7340032) { src = w; dst = wo; off = i - 4194304; }   // in_proj_w 3072x1024
    else                  { src = o; dst = oo; off = i - 7340032; }   // out_w 1024x1024
    float4 a = *(const float4*)(src + off);
    float4 b = *(const float4*)(src + off + 4);
    union { unsigned short s[8]; u32x4 v; } r;
    r.s[0] = f2bf(a.x); r.s[1] = f2bf(a.y); r.s[2] = f2bf(a.z); r.s[3] = f2bf(a.w);
    r.s[4] = f2bf(b.x); r.s[5] = f2bf(b.y); r.s[6] = f2bf(b.z); r.s[7] = f2bf(b.w);
    *(u32x4*)(dst + off) = r.v;
}

// ---------------------------------------------------------------- GEMM C = A * B^T + bias
// A [M][K] bf16, B [N][K] bf16, bias [N] f32. 128x128 tile, BK=64, 4 waves.
// LDS [128][64] bf16 with T2 XOR swizzle (16B-slot ^= row&7) via pre-swizzled
// global source of global_load_lds (rule #21).
// SCALE_Q: multiply output cols < 1024 by QSCALE (pre-scales Q for attention).
template <int STORE_BF16, int SCALE_Q>
__global__ __launch_bounds__(256) void k_gemm_bt(
    const unsigned short* __restrict__ A,
    const unsigned short* __restrict__ B,
    const float* __restrict__ bias,
    void* __restrict__ C,
    int M, int N, int K)
{
    __shared__ unsigned short As[128 * 64];
    __shared__ unsigned short Bs[128 * 64];
    const int tid = threadIdx.x;
    const int wid = tid >> 6, lane = tid & 63;
    const int m0 = blockIdx.y * 128, n0 = blockIdx.x * 128;

    const unsigned short* ag[4];
    const unsigned short* bg[4];
    unsigned lo[4];
#pragma unroll
    for (int j = 0; j < 4; ++j) {
        int o = (wid * 4 + j) * 1024 + lane * 16;  // byte offset in tile
        int r = o >> 7;                            // row (128B rows)
        int c = (o >> 4) & 7;                      // 16B slot
        int cs = (c ^ (r & 7)) * 8;                // pre-swizzled k-elem offset
        ag[j] = A + (long)(m0 + r) * K + cs;
        bg[j] = B + (long)(n0 + r) * K + cs;
        lo[j] = (unsigned)((wid * 4 + j) * 1024);
    }

    f32x4 acc[4][4] = {};
    const int wr = wid >> 1, wc = wid & 1;
    const int nk = K >> 6;

    for (int kt = 0; kt < nk; ++kt) {
#pragma unroll
        for (int j = 0; j < 4; ++j) {
            GLL(ag[j], (char*)As + lo[j]);
            GLL(bg[j], (char*)Bs + lo[j]);
            ag[j] += 64;
            bg[j] += 64;
        }
        __syncthreads();

        bf16x8 af[4][2], bfr[4][2];
#pragma unroll
        for (int i = 0; i < 4; ++i) {
            int ra = wr * 64 + i * 16 + (lane & 15);
            int rb = wc * 64 + i * 16 + (lane & 15);
#pragma unroll
            for (int kk = 0; kk < 2; ++kk) {
                int sa = ((kk * 4 + (lane >> 4)) ^ (ra & 7)) * 16;
                int sb = ((kk * 4 + (lane >> 4)) ^ (rb & 7)) * 16;
                af[i][kk]  = *(const bf16x8*)((char*)As + ra * 128 + sa);
                bfr[i][kk] = *(const bf16x8*)((char*)Bs + rb * 128 + sb);
            }
        }
#pragma unroll
        for (int kk = 0; kk < 2; ++kk)
#pragma unroll
            for (int mi = 0; mi < 4; ++mi)
#pragma unroll
                for (int ni = 0; ni < 4; ++ni)
                    acc[mi][ni] = __builtin_amdgcn_mfma_f32_16x16x32_bf16(
                        af[mi][kk], bfr[ni][kk], acc[mi][ni], 0, 0, 0);
        __syncthreads();
    }

#pragma unroll
    for (int mi = 0; mi < 4; ++mi)
#pragma unroll
        for (int ni = 0; ni < 4; ++ni) {
            int col = n0 + wc * 64 + ni * 16 + (lane & 15);
            float bv = bias[col];
            float scl = (SCALE_Q && col < 1024) ? QSCALE : 1.0f;
#pragma unroll
            for (int r = 0; r < 4; ++r) {
                int row = m0 + wr * 64 + mi * 16 + (lane >> 4) * 4 + r;
                float v = (acc[mi][ni][r] + bv) * scl;
                if (STORE_BF16)
                    ((unsigned short*)C)[(long)row * N + col] = f2bf(v);
                else
                    ((float*)C)[(long)row * N + col] = v;
            }
        }
}

// ---------------------------------------------------------------- V transpose (sigma'-permuted)
// qkv v-part [t][d] -> Vt[b][h][d][64-tile sigma' positions].
// sigma' matches the in-register P fragment k-indexing of the swapped-QK attn:
//   pos p (a=p>>5, g=(p>>3)&3, b=(p>>2)&1, r=p&3) holds t = 4g + r + 16*(2a+b).
__global__ __launch_bounds__(256) void k_transpose_v(
    const unsigned short* __restrict__ qkv, unsigned short* __restrict__ Vt)
{
    __shared__ unsigned short tile[64 * 64];
    const int bh = blockIdx.x >> 5, tt = blockIdx.x & 31;
    const int b = bh >> 4, h = bh & 15;
    const int tid = threadIdx.x;

    {
        int tr = tid >> 3;     // 0..31
        int s0 = tid & 7;      // 16B slot
#pragma unroll
        for (int rr = 0; rr < 2; ++rr) {
            int t = tr + rr * 32;
            u32x4 v = *(const u32x4*)(qkv + ((long)(tt * 64 + t) * 2 + b) * 3072 + 2048 + h * 64 + s0 * 8);
            int slot = s0 ^ (t & 7) ^ ((t >> 3) & 7);
            *(u32x4*)((char*)tile + t * 128 + slot * 16) = v;
        }
    }
    __syncthreads();
    {
        int d = tid >> 3;      // 0..31
        int t8 = (tid & 7) * 8;
#pragma unroll
        for (int rr = 0; rr < 2; ++rr) {
            int dd = d + rr * 32;
            union { unsigned short s[8]; u32x4 v; } r;
#pragma unroll
            for (int i = 0; i < 8; ++i) {
                int pos = t8 + i;
                int t = 4 * ((pos >> 3) & 3) + (pos & 3) + 16 * (2 * (pos >> 5) + ((pos >> 2) & 1));
                int slot = (dd >> 3) ^ (t & 7) ^ ((t >> 3) & 7);
                r.s[i] = *(const unsigned short*)((char*)tile + t * 128 + slot * 16 + (dd & 7) * 2);
            }
            *(u32x4*)(Vt + ((long)bh * 64 + dd) * 2048 + tt * 64 + t8) = r.v;
        }
    }
}

// ---------------------------------------------------------------- flash attention v7
// grid 1024 = 32 (b,h) x 32 q-tiles of 64 rows; 4 waves x 16 q-rows each.
// -> 4 blocks/CU, 16 waves/CU (4/SIMD) for TLP; serial QK->exp->PV chains of
// independent blocks interleave. Per-wave math = v6 with the mi dim deleted.
// Swapped QK^T (S^T in regs), in-register P pack, shuffle-free row-sum,
// double-buffered K/V with counted vmcnt; s_setprio around MFMA clusters (T5).
__global__ __launch_bounds__(256, 2) void k_attn(
    const unsigned short* __restrict__ qkv,
    const unsigned short* __restrict__ Vt,
    unsigned short* __restrict__ attn)
{
    __shared__ unsigned short Ks[2 * 64 * 64];  // 16KB [buf][s][d] swizzled
    __shared__ unsigned short Vs[2 * 64 * 64];  // 16KB [buf][d][pos] swizzled
    const int tid = threadIdx.x, wid = tid >> 6, lane = tid & 63;
    const int bh = blockIdx.x >> 5, tq = blockIdx.x & 31;
    const int b = bh >> 4, h = bh & 15;

    // Q fragments (B-operand: lane holds q-row = lane&15, k-elems (lane>>4)*8)
    bf16x8 qf[2];
#pragma unroll
    for (int kk = 0; kk < 2; ++kk) {
        int t = tq * 64 + wid * 16 + (lane & 15);
        qf[kk] = *(const bf16x8*)(qkv + (long)(t * 2 + b) * 3072 + h * 64 + kk * 32 + (lane >> 4) * 8);
    }

    // staging: wave wid stages 2 x 1KB chunks of each of Ks, Vs
    const unsigned short* kg[2];
    const unsigned short* vg[2];
    unsigned lo[2];
#pragma unroll
    for (int j = 0; j < 2; ++j) {
        int o = (wid * 2 + j) * 1024 + lane * 16;
        int r = o >> 7, c = (o >> 4) & 7;
        int cs = (c ^ (r & 7)) * 8;
        kg[j] = qkv + (long)(r * 2 + b) * 3072 + 1024 + h * 64 + cs;
        vg[j] = Vt + ((long)bh * 64 + r) * 2048 + cs;
        lo[j] = (unsigned)((wid * 2 + j) * 1024);
    }

    f32x4 acc[4] = {};
    float suma = 0.f;

    // prologue: stage tile 0 into buf 0
#pragma unroll
    for (int j = 0; j < 2; ++j) {
        GLL(kg[j], (char*)Ks + lo[j]);
        GLL(vg[j], (char*)Vs + lo[j]);
        kg[j] += 64 * 6144;
        vg[j] += 64;
    }

    for (int st = 0; st < 32; ++st) {
        const int cur = st & 1;
        if (st < 31) {
#pragma unroll
            for (int j = 0; j < 2; ++j) {
                GLL(kg[j], (char*)Ks + (cur ^ 1) * 8192 + lo[j]);
                GLL(vg[j], (char*)Vs + (cur ^ 1) * 8192 + lo[j]);
                kg[j] += 64 * 6144;
                vg[j] += 64;
            }
            asm volatile("s_waitcnt vmcnt(4)" ::: "memory");  // tile st landed
        } else {
            asm volatile("s_waitcnt vmcnt(0)" ::: "memory");
        }
        __builtin_amdgcn_s_barrier();

        const char* kbase = (const char*)Ks + cur * 8192;
        const char* vbase = (const char*)Vs + cur * 8192;

        // QK^T swapped: sc[ni] = S^T block; lane: q=lane&15, s=(lane>>4)*4+r+16ni
        bf16x8 kf[4][2];
#pragma unroll
        for (int ni = 0; ni < 4; ++ni) {
            int row = ni * 16 + (lane & 15);
#pragma unroll
            for (int kk = 0; kk < 2; ++kk) {
                int sl = ((kk * 4 + (lane >> 4)) ^ (row & 7)) * 16;
                kf[ni][kk] = *(const bf16x8*)(kbase + row * 128 + sl);
            }
        }
        f32x4 sc[4] = {};
        __builtin_amdgcn_s_setprio(1);
#pragma unroll
        for (int kk = 0; kk < 2; ++kk)
#pragma unroll
            for (int ni = 0; ni < 4; ++ni)
                sc[ni] = __builtin_amdgcn_mfma_f32_16x16x32_bf16(
                    kf[ni][kk], qf[kk], sc[ni], 0, 0, 0);
        __builtin_amdgcn_s_setprio(0);

        // exp2 + in-register pack into PV B-fragments; in-lane row-sum
        float ex[4][4];
        float part = 0.f;
#pragma unroll
        for (int ni = 0; ni < 4; ++ni)
#pragma unroll
            for (int r = 0; r < 4; ++r) {
                float e = EXP2(sc[ni][r]);
                ex[ni][r] = e;
                part += e;
            }
        suma += part;
        bf16x8 pfrag[2];
#pragma unroll
        for (int a = 0; a < 2; ++a) {
            union { uint32_t u[4]; bf16x8 v; } pk;
            pk.u[0] = (uint32_t)f2bf(ex[2 * a][0])     | ((uint32_t)f2bf(ex[2 * a][1]) << 16);
            pk.u[1] = (uint32_t)f2bf(ex[2 * a][2])     | ((uint32_t)f2bf(ex[2 * a][3]) << 16);
            pk.u[2] = (uint32_t)f2bf(ex[2 * a + 1][0]) | ((uint32_t)f2bf(ex[2 * a + 1][1]) << 16);
            pk.u[3] = (uint32_t)f2bf(ex[2 * a + 1][2]) | ((uint32_t)f2bf(ex[2 * a + 1][3]) << 16);
            pfrag[a] = pk.v;
        }

        // PV: acc[nd] (= O^T block) += Vt-frag x P-frag
        bf16x8 vf[4][2];
#pragma unroll
        for (int nd = 0; nd < 4; ++nd) {
            int row = nd * 16 + (lane & 15);
#pragma unroll
            for (int a = 0; a < 2; ++a) {
                int sl = ((a * 4 + (lane >> 4)) ^ (row & 7)) * 16;
                vf[nd][a] = *(const bf16x8*)(vbase + row * 128 + sl);
            }
        }
        __builtin_amdgcn_s_setprio(1);
#pragma unroll
        for (int a = 0; a < 2; ++a)
#pragma unroll
            for (int nd = 0; nd < 4; ++nd)
                acc[nd] = __builtin_amdgcn_mfma_f32_16x16x32_bf16(
                    vf[nd][a], pfrag[a], acc[nd], 0, 0, 0);
        __builtin_amdgcn_s_setprio(0);
        __builtin_amdgcn_s_barrier();
    }

    // cross-lane row-sum completion (lanes l, l^16, l^32, l^48 share q)
    suma += __shfl_xor(suma, 16, 64);
    suma += __shfl_xor(suma, 32, 64);

    // epilogue: O^T normalize + store; lane: q=lane&15, d=(lane>>4)*4+r+16nd
    {
        float inv = 1.0f / suma;
        int t = tq * 64 + wid * 16 + (lane & 15);
#pragma unroll
        for (int nd = 0; nd < 4; ++nd) {
            int e = h * 64 + nd * 16 + (lane >> 4) * 4;
            u32x2 w;
            w.x = (uint32_t)f2bf(acc[nd][0] * inv) | ((uint32_t)f2bf(acc[nd][1] * inv) << 16);
            w.y = (uint32_t)f2bf(acc[nd][2] * inv) | ((uint32_t)f2bf(acc[nd][3] * inv) << 16);
            *(u32x2*)(attn + (long)(t * 2 + b) * 1024 + e) = w;
        }
    }
}

// ---------------------------------------------------------------- launch
extern "C" void kernel_launch(void* const* d_in, const int* in_sizes, int n_in,
                              void* d_out, int out_size, void* d_ws, size_t ws_size,
                              hipStream_t stream) {
    const float* query = (const float*)d_in[0];
    const float* ipw   = (const float*)d_in[3];
    const float* ipb   = (const float*)d_in[4];
    const float* ow    = (const float*)d_in[5];
    const float* ob    = (const float*)d_in[6];
    float* out = (float*)d_out;

    char* ws = (char*)d_ws;
    unsigned short* Xb   = (unsigned short*)(ws);                 //  8 MB  [4096][1024]
    unsigned short* Wb   = (unsigned short*)(ws + (8l << 20));    //  6 MB  [3072][1024]
    unsigned short* OWb  = (unsigned short*)(ws + (14l << 20));   //  2 MB  [1024][1024]
    unsigned short* qkvp = (unsigned short*)(ws + (16l << 20));   // 24 MB  [4096][3072]
    unsigned short* Vtp  = (unsigned short*)(ws + (40l << 20));   //  8 MB  [32][64][2048]
    unsigned short* attn = (unsigned short*)(ws + (48l << 20));   //  8 MB  [4096][1024]

    k_cvt3<<<4096, 256, 0, stream>>>(query, ipw, ow, Xb, Wb, OWb);

    k_gemm_bt<1, 1><<<dim3(QKVN / 128, MROWS / 128), 256, 0, stream>>>(
        Xb, Wb, ipb, qkvp, MROWS, QKVN, E_DIM);

    k_transpose_v<<<1024, 256, 0, stream>>>(qkvp, Vtp);

    k_attn<<<1024, 256, 0, stream>>>(qkvp, Vtp, attn);

    k_gemm_bt<0, 0><<<dim3(E_DIM / 128, MROWS / 128), 256, 0, stream>>>(
        attn, OWb, ob, out, MROWS, E_DIM, E_DIM);
}

// Round 12
// 218.270 us; speedup vs baseline: 1.0263x; 1.0263x over previous
//
#include <hip/hip_runtime.h>
#include <hip/hip_bf16.h>
#include <stdint.h>
#include <math.h>

// Problem constants
#define T_DIM 2048
#define B_DIM 2
#define E_DIM 1024
#define H_DIM 16
#define DH    64
#define MROWS (T_DIM * B_DIM)   // 4096
#define QKVN  (3 * E_DIM)       // 3072

typedef __attribute__((ext_vector_type(8))) __bf16 bf16x8;
typedef __attribute__((ext_vector_type(4))) float f32x4;
typedef __attribute__((ext_vector_type(4))) uint32_t u32x4;
typedef __attribute__((ext_vector_type(2))) uint32_t u32x2;

typedef __attribute__((address_space(1))) const uint32_t gu32;
typedef __attribute__((address_space(3))) uint32_t lu32;

// async global->LDS, 16B per lane; LDS dest = wave-uniform base + lane*16
#define GLL(gp, lp) __builtin_amdgcn_global_load_lds((gu32*)(gp), (lu32*)(lp), 16, 0, 0)

// Q prescale: 0.125 (=DH^-0.5) * log2(e), so attn uses exp2 (bare v_exp_f32)
#define QSCALE 0.18033688011112042f

// raw 2^x (v_exp_f32). Guarded: builtin if present, else OCML exp2f.
#if __has_builtin(__builtin_amdgcn_exp2f)
#define EXP2(x) __builtin_amdgcn_exp2f(x)
#else
#define EXP2(x) exp2f(x)
#endif

static __device__ __forceinline__ unsigned short f2bf(float f) {
    uint32_t u = __float_as_uint(f);
    u += 0x7FFFu + ((u >> 16) & 1u);   // RNE
    return (unsigned short)(u >> 16);
}

// ---------------------------------------------------------------- fused fp32 -> bf16 (3 tensors)
__global__ void k_cvt3(const float* __restrict__ q,  const float* __restrict__ w,
                       const float* __restrict__ o,
                       unsigned short* __restrict__ qo, unsigned short* __restrict__ wo,
                       unsigned short* __restrict__ oo) {
    long i = (long)(blockIdx.x * 256 + threadIdx.x) * 8;
    const float* src; unsigned short* dst; long off;
    if (i < 4194304)      { src = q; dst = qo; off = i; }             // query 4096x1024
    else if (i < 7340032) { src = w; dst = wo; off = i - 4194304; }   // in_proj_w 3072x1024
    else                  { src = o; dst = oo; off = i - 7340032; }   // out_w 1024x1024
    float4 a = *(const float4*)(src + off);
    float4 b = *(const float4*)(src + off + 4);
    union { unsigned short s[8]; u32x4 v; } r;
    r.s[0] = f2bf(a.x); r.s[1] = f2bf(a.y); r.s[2] = f2bf(a.z); r.s[3] = f2bf(a.w);
    r.s[4] = f2bf(b.x); r.s[5] = f2bf(b.y); r.s[6] = f2bf(b.z); r.s[7] = f2bf(b.w);
    *(u32x4*)(dst + off) = r.v;
}

// ---------------------------------------------------------------- GEMM C = A * B^T + bias
// A [M][K] bf16, B [N][K] bf16, bias [N] f32. Tile BM x 128 (BM = MI*32),
// BK=64, 4 waves as 2x2 of (MI*16) x 64. LDS XOR swizzle via pre-swizzled
// global source of global_load_lds (rule #21).
// SCALE_Q: multiply output cols < 1024 by QSCALE (pre-scales Q for attention).
// MI=4 -> BM=128 (QKV GEMM, 768 blocks = 3/CU). MI=2 -> BM=64 (out-proj,
// grid 512 = 2 blocks/CU -- fixes the 1-block/CU overlap starvation).
template <int STORE_BF16, int SCALE_Q, int MI>
__global__ __launch_bounds__(256) void k_gemm_bt(
    const unsigned short* __restrict__ A,
    const unsigned short* __restrict__ B,
    const float* __restrict__ bias,
    void* __restrict__ C,
    int M, int N, int K)
{
    __shared__ unsigned short As[MI * 32 * 64];
    __shared__ unsigned short Bs[128 * 64];
    const int tid = threadIdx.x;
    const int wid = tid >> 6, lane = tid & 63;
    const int m0 = blockIdx.y * (MI * 32), n0 = blockIdx.x * 128;

    const unsigned short* ag[MI];
    const unsigned short* bg[4];
    unsigned loA[MI], loB[4];
#pragma unroll
    for (int j = 0; j < MI; ++j) {
        int o = (wid * MI + j) * 1024 + lane * 16;  // byte offset in A tile
        int r = o >> 7;                             // row (128B rows)
        int c = (o >> 4) & 7;                       // 16B slot
        int cs = (c ^ (r & 7)) * 8;                 // pre-swizzled k-elem offset
        ag[j] = A + (long)(m0 + r) * K + cs;
        loA[j] = (unsigned)((wid * MI + j) * 1024);
    }
#pragma unroll
    for (int j = 0; j < 4; ++j) {
        int o = (wid * 4 + j) * 1024 + lane * 16;
        int r = o >> 7;
        int c = (o >> 4) & 7;
        int cs = (c ^ (r & 7)) * 8;
        bg[j] = B + (long)(n0 + r) * K + cs;
        loB[j] = (unsigned)((wid * 4 + j) * 1024);
    }

    f32x4 acc[MI][4] = {};
    const int wr = wid >> 1, wc = wid & 1;
    const int nk = K >> 6;

    for (int kt = 0; kt < nk; ++kt) {
#pragma unroll
        for (int j = 0; j < MI; ++j) {
            GLL(ag[j], (char*)As + loA[j]);
            ag[j] += 64;
        }
#pragma unroll
        for (int j = 0; j < 4; ++j) {
            GLL(bg[j], (char*)Bs + loB[j]);
            bg[j] += 64;
        }
        __syncthreads();

        bf16x8 af[MI][2], bfr[4][2];
#pragma unroll
        for (int i = 0; i < MI; ++i) {
            int ra = wr * (MI * 16) + i * 16 + (lane & 15);
#pragma unroll
            for (int kk = 0; kk < 2; ++kk) {
                int sa = ((kk * 4 + (lane >> 4)) ^ (ra & 7)) * 16;
                af[i][kk] = *(const bf16x8*)((char*)As + ra * 128 + sa);
            }
        }
#pragma unroll
        for (int i = 0; i < 4; ++i) {
            int rb = wc * 64 + i * 16 + (lane & 15);
#pragma unroll
            for (int kk = 0; kk < 2; ++kk) {
                int sb = ((kk * 4 + (lane >> 4)) ^ (rb & 7)) * 16;
                bfr[i][kk] = *(const bf16x8*)((char*)Bs + rb * 128 + sb);
            }
        }
#pragma unroll
        for (int kk = 0; kk < 2; ++kk)
#pragma unroll
            for (int mi = 0; mi < MI; ++mi)
#pragma unroll
                for (int ni = 0; ni < 4; ++ni)
                    acc[mi][ni] = __builtin_amdgcn_mfma_f32_16x16x32_bf16(
                        af[mi][kk], bfr[ni][kk], acc[mi][ni], 0, 0, 0);
        __syncthreads();
    }

#pragma unroll
    for (int mi = 0; mi < MI; ++mi)
#pragma unroll
        for (int ni = 0; ni < 4; ++ni) {
            int col = n0 + wc * 64 + ni * 16 + (lane & 15);
            float bv = bias[col];
            float scl = (SCALE_Q && col < 1024) ? QSCALE : 1.0f;
#pragma unroll
            for (int r = 0; r < 4; ++r) {
                int row = m0 + wr * (MI * 16) + mi * 16 + (lane >> 4) * 4 + r;
                float v = (acc[mi][ni][r] + bv) * scl;
                if (STORE_BF16)
                    ((unsigned short*)C)[(long)row * N + col] = f2bf(v);
                else
                    ((float*)C)[(long)row * N + col] = v;
            }
        }
}

// ---------------------------------------------------------------- V transpose (sigma'-permuted)
// qkv v-part [t][d] -> Vt[b][h][d][64-tile sigma' positions].
// sigma' matches the in-register P fragment k-indexing of the swapped-QK attn:
//   pos p (a=p>>5, g=(p>>3)&3, b=(p>>2)&1, r=p&3) holds t = 4g + r + 16*(2a+b).
__global__ __launch_bounds__(256) void k_transpose_v(
    const unsigned short* __restrict__ qkv, unsigned short* __restrict__ Vt)
{
    __shared__ unsigned short tile[64 * 64];
    const int bh = blockIdx.x >> 5, tt = blockIdx.x & 31;
    const int b = bh >> 4, h = bh & 15;
    const int tid = threadIdx.x;

    {
        int tr = tid >> 3;     // 0..31
        int s0 = tid & 7;      // 16B slot
#pragma unroll
        for (int rr = 0; rr < 2; ++rr) {
            int t = tr + rr * 32;
            u32x4 v = *(const u32x4*)(qkv + ((long)(tt * 64 + t) * 2 + b) * 3072 + 2048 + h * 64 + s0 * 8);
            int slot = s0 ^ (t & 7) ^ ((t >> 3) & 7);
            *(u32x4*)((char*)tile + t * 128 + slot * 16) = v;
        }
    }
    __syncthreads();
    {
        int d = tid >> 3;      // 0..31
        int t8 = (tid & 7) * 8;
#pragma unroll
        for (int rr = 0; rr < 2; ++rr) {
            int dd = d + rr * 32;
            union { unsigned short s[8]; u32x4 v; } r;
#pragma unroll
            for (int i = 0; i < 8; ++i) {
                int pos = t8 + i;
                int t = 4 * ((pos >> 3) & 3) + (pos & 3) + 16 * (2 * (pos >> 5) + ((pos >> 2) & 1));
                int slot = (dd >> 3) ^ (t & 7) ^ ((t >> 3) & 7);
                r.s[i] = *(const unsigned short*)((char*)tile + t * 128 + slot * 16 + (dd & 7) * 2);
            }
            *(u32x4*)(Vt + ((long)bh * 64 + dd) * 2048 + tt * 64 + t8) = r.v;
        }
    }
}

// ---------------------------------------------------------------- flash attention (R9 version)
// grid 512 = 32 (b,h) x 16 q-tiles of 128 rows; 4 waves x 32 q-rows each.
// Swapped QK^T (S^T in regs), in-register P pack, shuffle-free row-sum,
// double-buffered K/V with counted vmcnt. Measured 57.4 us (round 9).
__global__ __launch_bounds__(256, 2) void k_attn(
    const unsigned short* __restrict__ qkv,
    const unsigned short* __restrict__ Vt,
    unsigned short* __restrict__ attn)
{
    __shared__ unsigned short Ks[2 * 64 * 64];  // 16KB [buf][s][d] swizzled
    __shared__ unsigned short Vs[2 * 64 * 64];  // 16KB [buf][d][pos] swizzled
    const int tid = threadIdx.x, wid = tid >> 6, lane = tid & 63;
    const int bh = blockIdx.x >> 4, tq = blockIdx.x & 15;
    const int b = bh >> 4, h = bh & 15;

    // Q fragments (B-operand: lane holds q-row = lane&15, k-elems (lane>>4)*8)
    bf16x8 qf[2][2];
#pragma unroll
    for (int mi = 0; mi < 2; ++mi)
#pragma unroll
        for (int kk = 0; kk < 2; ++kk) {
            int t = tq * 128 + wid * 32 + mi * 16 + (lane & 15);
            qf[mi][kk] = *(const bf16x8*)(qkv + (long)(t * 2 + b) * 3072 + h * 64 + kk * 32 + (lane >> 4) * 8);
        }

    // staging: wave wid stages 2 x 1KB chunks of each of Ks, Vs
    const unsigned short* kg[2];
    const unsigned short* vg[2];
    unsigned lo[2];
#pragma unroll
    for (int j = 0; j < 2; ++j) {
        int o = (wid * 2 + j) * 1024 + lane * 16;
        int r = o >> 7, c = (o >> 4) & 7;
        int cs = (c ^ (r & 7)) * 8;
        kg[j] = qkv + (long)(r * 2 + b) * 3072 + 1024 + h * 64 + cs;
        vg[j] = Vt + ((long)bh * 64 + r) * 2048 + cs;
        lo[j] = (unsigned)((wid * 2 + j) * 1024);
    }

    f32x4 acc[2][4] = {};
    float suma[2] = {0.f, 0.f};

    // prologue: stage tile 0 into buf 0
#pragma unroll
    for (int j = 0; j < 2; ++j) {
        GLL(kg[j], (char*)Ks + lo[j]);
        GLL(vg[j], (char*)Vs + lo[j]);
        kg[j] += 64 * 6144;
        vg[j] += 64;
    }

    for (int st = 0; st < 32; ++st) {
        const int cur = st & 1;
        if (st < 31) {
#pragma unroll
            for (int j = 0; j < 2; ++j) {
                GLL(kg[j], (char*)Ks + (cur ^ 1) * 8192 + lo[j]);
                GLL(vg[j], (char*)Vs + (cur ^ 1) * 8192 + lo[j]);
                kg[j] += 64 * 6144;
                vg[j] += 64;
            }
            asm volatile("s_waitcnt vmcnt(4)" ::: "memory");  // tile st landed
        } else {
            asm volatile("s_waitcnt vmcnt(0)" ::: "memory");
        }
        __builtin_amdgcn_s_barrier();

        const char* kbase = (const char*)Ks + cur * 8192;
        const char* vbase = (const char*)Vs + cur * 8192;

        // QK^T swapped: sc[mi][ni] = S^T block, lane: q=lane&15, s=(lane>>4)*4+r+16ni
        bf16x8 kf[4][2];
#pragma unroll
        for (int ni = 0; ni < 4; ++ni) {
            int row = ni * 16 + (lane & 15);
#pragma unroll
            for (int kk = 0; kk < 2; ++kk) {
                int sl = ((kk * 4 + (lane >> 4)) ^ (row & 7)) * 16;
                kf[ni][kk] = *(const bf16x8*)(kbase + row * 128 + sl);
            }
        }
        f32x4 sc[2][4] = {};
#pragma unroll
        for (int kk = 0; kk < 2; ++kk)
#pragma unroll
            for (int mi = 0; mi < 2; ++mi)
#pragma unroll
                for (int ni = 0; ni < 4; ++ni)
                    sc[mi][ni] = __builtin_amdgcn_mfma_f32_16x16x32_bf16(
                        kf[ni][kk], qf[mi][kk], sc[mi][ni], 0, 0, 0);

        // exp2 + in-register pack into PV B-fragments; in-lane row-sum
        bf16x8 pfrag[2][2];
#pragma unroll
        for (int mi = 0; mi < 2; ++mi) {
            float ex[4][4];
            float part = 0.f;
#pragma unroll
            for (int ni = 0; ni < 4; ++ni)
#pragma unroll
                for (int r = 0; r < 4; ++r) {
                    float e = EXP2(sc[mi][ni][r]);
                    ex[ni][r] = e;
                    part += e;
                }
            suma[mi] += part;
#pragma unroll
            for (int a = 0; a < 2; ++a) {
                union { uint32_t u[4]; bf16x8 v; } pk;
                pk.u[0] = (uint32_t)f2bf(ex[2 * a][0])     | ((uint32_t)f2bf(ex[2 * a][1]) << 16);
                pk.u[1] = (uint32_t)f2bf(ex[2 * a][2])     | ((uint32_t)f2bf(ex[2 * a][3]) << 16);
                pk.u[2] = (uint32_t)f2bf(ex[2 * a + 1][0]) | ((uint32_t)f2bf(ex[2 * a + 1][1]) << 16);
                pk.u[3] = (uint32_t)f2bf(ex[2 * a + 1][2]) | ((uint32_t)f2bf(ex[2 * a + 1][3]) << 16);
                pfrag[mi][a] = pk.v;
            }
        }

        // PV: acc[mi][nd] (= O^T block) += Vt-frag x P-frag
        bf16x8 vf[4][2];
#pragma unroll
        for (int nd = 0; nd < 4; ++nd) {
            int row = nd * 16 + (lane & 15);
#pragma unroll
            for (int a = 0; a < 2; ++a) {
                int sl = ((a * 4 + (lane >> 4)) ^ (row & 7)) * 16;
                vf[nd][a] = *(const bf16x8*)(vbase + row * 128 + sl);
            }
        }
#pragma unroll
        for (int a = 0; a < 2; ++a)
#pragma unroll
            for (int mi = 0; mi < 2; ++mi)
#pragma unroll
                for (int nd = 0; nd < 4; ++nd)
                    acc[mi][nd] = __builtin_amdgcn_mfma_f32_16x16x32_bf16(
                        vf[nd][a], pfrag[mi][a], acc[mi][nd], 0, 0, 0);
        __builtin_amdgcn_s_barrier();
    }

    // cross-lane row-sum completion (lanes l, l^16, l^32, l^48 share q)
#pragma unroll
    for (int mi = 0; mi < 2; ++mi) {
        suma[mi] += __shfl_xor(suma[mi], 16, 64);
        suma[mi] += __shfl_xor(suma[mi], 32, 64);
    }

    // epilogue: O^T normalize + store; lane: q=lane&15, d=(lane>>4)*4+r+16nd
#pragma unroll
    for (int mi = 0; mi < 2; ++mi) {
        float inv = 1.0f / suma[mi];
        int t = tq * 128 + wid * 32 + mi * 16 + (lane & 15);
#pragma unroll
        for (int nd = 0; nd < 4; ++nd) {
            int e = h * 64 + nd * 16 + (lane >> 4) * 4;
            u32x2 w;
            w.x = (uint32_t)f2bf(acc[mi][nd][0] * inv) | ((uint32_t)f2bf(acc[mi][nd][1] * inv) << 16);
            w.y = (uint32_t)f2bf(acc[mi][nd][2] * inv) | ((uint32_t)f2bf(acc[mi][nd][3] * inv) << 16);
            *(u32x2*)(attn + (long)(t * 2 + b) * 1024 + e) = w;
        }
    }
}

// ---------------------------------------------------------------- launch
extern "C" void kernel_launch(void* const* d_in, const int* in_sizes, int n_in,
                              void* d_out, int out_size, void* d_ws, size_t ws_size,
                              hipStream_t stream) {
    const float* query = (const float*)d_in[0];
    const float* ipw   = (const float*)d_in[3];
    const float* ipb   = (const float*)d_in[4];
    const float* ow    = (const float*)d_in[5];
    const float* ob    = (const float*)d_in[6];
    float* out = (float*)d_out;

    char* ws = (char*)d_ws;
    unsigned short* Xb   = (unsigned short*)(ws);                 //  8 MB  [4096][1024]
    unsigned short* Wb   = (unsigned short*)(ws + (8l << 20));    //  6 MB  [3072][1024]
    unsigned short* OWb  = (unsigned short*)(ws + (14l << 20));   //  2 MB  [1024][1024]
    unsigned short* qkvp = (unsigned short*)(ws + (16l << 20));   // 24 MB  [4096][3072]
    unsigned short* Vtp  = (unsigned short*)(ws + (40l << 20));   //  8 MB  [32][64][2048]
    unsigned short* attn = (unsigned short*)(ws + (48l << 20));   //  8 MB  [4096][1024]

    k_cvt3<<<4096, 256, 0, stream>>>(query, ipw, ow, Xb, Wb, OWb);

    // QKV: BM=128 (MI=4), grid 24x32 = 768 blocks = 3/CU
    k_gemm_bt<1, 1, 4><<<dim3(QKVN / 128, MROWS / 128), 256, 0, stream>>>(
        Xb, Wb, ipb, qkvp, MROWS, QKVN, E_DIM);

    k_transpose_v<<<1024, 256, 0, stream>>>(qkvp, Vtp);

    k_attn<<<512, 256, 0, stream>>>(qkvp, Vtp, attn);

    // out-proj: BM=64 (MI=2), grid 8x64 = 512 blocks = 2/CU (was 256 = 1/CU)
    k_gemm_bt<0, 0, 2><<<dim3(E_DIM / 128, MROWS / 64), 256, 0, stream>>>(
        attn, OWb, ob, out, MROWS, E_DIM, E_DIM);
}